// Round 12
// baseline (294.993 us; speedup 1.0000x reference)
//
#include <hip/hip_runtime.h>
#include <hip/hip_bf16.h>

// (B,T,C,H) = (4,2048,1024,16), D=64
#define Bb 4
#define Tt 2048
#define Cc 1024
#define Hh 16

typedef unsigned short u16;
typedef __attribute__((ext_vector_type(8))) __bf16 bf16x8;
typedef __attribute__((ext_vector_type(4))) float  f32x4;

__device__ __forceinline__ u16 f2bf_hw(float f) {         // native cvt on gfx950
    __bf16 h = (__bf16)f;
    return *(u16*)&h;
}

// v_cvt_pk_bf16_f32: low16 = bf16(a), high16 = bf16(b)
__device__ __forceinline__ unsigned cvt_pk_bf16(float a, float b) {
    unsigned r;
    asm("v_cvt_pk_bf16_f32 %0, %1, %2" : "=v"(r) : "v"(a), "v"(b));
    return r;
}

__device__ __forceinline__ float fexp2(float x) {
#if __has_builtin(__builtin_amdgcn_exp2f)
    return __builtin_amdgcn_exp2f(x);
#else
    return __expf(x * 0.6931471805599453f);
#endif
}

__device__ __forceinline__ void gld_lds16(const void* g, void* l) {
    __builtin_amdgcn_global_load_lds(
        (__attribute__((address_space(1))) void*)(g),
        (__attribute__((address_space(3))) void*)(l),
        16, 0, 0);
}

__device__ __forceinline__ f32x4 mfma16(bf16x8 a, bf16x8 b, f32x4 c) {
    return __builtin_amdgcn_mfma_f32_16x16x32_bf16(a, b, c, 0, 0, 0);
}

// ---------------------------------------------------------------------------
// Fused preprocessing: one launch replaces cast_f32_bf16 + castT(w_qkv) +
// castT(w_out). Round-11 observation: kernel-time sum (~180us) vs total
// (~253us) implies ~70us of dispatch overhead — cut launches 6 -> 4.
// Region decode on 1D grid: [0,8192) cast-x; [8192,8960) castT w_qkv;
// [8960,9216) castT w_out.
// ---------------------------------------------------------------------------
__device__ void castT_body(const float* __restrict__ in, u16* __restrict__ out,
                           int K, int N, int scaleN, float sv,
                           int bx, int by, float Ls[64][65]) {
    const int n0 = bx * 64, k0 = by * 64;
    const int t = threadIdx.x;
    #pragma unroll
    for (int s = 0; s < 4; ++s) {
        int idx = t + 256 * s;
        int r   = idx >> 4;
        int c4  = (idx & 15) * 4;
        float4 v = *(const float4*)&in[(size_t)(k0 + r) * N + n0 + c4];
        Ls[r][c4 + 0] = v.x; Ls[r][c4 + 1] = v.y;
        Ls[r][c4 + 2] = v.z; Ls[r][c4 + 3] = v.w;
    }
    __syncthreads();
    #pragma unroll
    for (int s = 0; s < 2; ++s) {
        int idx = t + 256 * s;
        int n   = idx >> 3;
        int kc  = (idx & 7) * 8;
        const float sc = (n0 + n < scaleN) ? sv : 1.0f;
        alignas(16) u16 tmp[8];
        #pragma unroll
        for (int i = 0; i < 8; ++i) tmp[i] = f2bf_hw(Ls[kc + i][n] * sc);
        *(uint4*)&out[(size_t)(n0 + n) * K + k0 + kc] = *(const uint4*)tmp;
    }
}

__global__ void prep_cast(const float* __restrict__ x, u16* __restrict__ xb,
                          const float* __restrict__ w_qkv, u16* __restrict__ wqkvT,
                          const float* __restrict__ w_out, u16* __restrict__ woutT,
                          float c2) {
    __shared__ float Ls[64][65];
    const int id = blockIdx.x;
    if (id < 8192) {
        // cast x [M,C] f32 -> bf16, 4 f32/thread; 8192*256*4 = exactly M*C
        const int i = id * 256 + threadIdx.x;
        float4 v = ((const float4*)x)[i];
        uint2 o;
        o.x = cvt_pk_bf16(v.x, v.y);
        o.y = cvt_pk_bf16(v.z, v.w);
        ((uint2*)xb)[i] = o;
    } else if (id < 8192 + 768) {
        const int r = id - 8192;                 // 48 x 16
        castT_body(w_qkv, wqkvT, Cc, 3 * Cc, Cc, c2, r % 48, r / 48, Ls);
    } else {
        const int r = id - 8960;                 // 16 x 16
        castT_body(w_out, woutT, Cc, Cc, 0, 1.0f, r % 16, r / 16, Ls);
    }
}

// ---------------------------------------------------------------------------
// bf16 GEMM, B^T input — BK=64 m97 structure (round-10 win: 32->16 drain
// points, 128^2 tile, 3 blocks/CU). gemm2 only.
// ---------------------------------------------------------------------------
__global__ __launch_bounds__(256, 3) void gemm_bt_bf16(
    const u16* __restrict__ A, const u16* __restrict__ Bt,
    const float* __restrict__ bias,
    u16* __restrict__ outB, float* __restrict__ outF,
    int M, int N, int K)
{
    __shared__ u16 As[128 * 64];
    __shared__ u16 Bs[128 * 64];
    const int t = threadIdx.x;
    const int w = t >> 6, lane = t & 63;
    const int quad = lane >> 4, l16 = lane & 15;
    const int wm = w >> 1, wn = w & 1;
    const int m0 = blockIdx.y * 128, n0 = blockIdx.x * 128;

    const int l8r   = lane >> 3;
    const int g_log = (lane & 7) ^ l8r;
    const u16* sAp[4]; const u16* sBp[4];
    #pragma unroll
    for (int u = 0; u < 4; ++u) {
        const int gi = w * 4 + u;                     // [0,16)
        sAp[u] = A  + (size_t)(m0 + gi * 8 + l8r) * K + g_log * 8;
        sBp[u] = Bt + (size_t)(n0 + gi * 8 + l8r) * K + g_log * 8;
    }
    const int dst0 = w * 2048 + lane * 8;             // u16 units

    int aoff[4][2], boff[4][2];
    #pragma unroll
    for (int i = 0; i < 4; ++i) {
        const int rA = 64 * wm + 16 * i + l16;
        const int rB = 64 * wn + 16 * i + l16;
        #pragma unroll
        for (int kk = 0; kk < 2; ++kk) {
            aoff[i][kk] = rA * 64 + (((4 * kk + quad) ^ (rA & 7)) * 8);
            boff[i][kk] = rB * 64 + (((4 * kk + quad) ^ (rB & 7)) * 8);
        }
    }

    f32x4 acc[4][4] = {};

    for (int k0 = 0; k0 < K; k0 += 64) {
        __syncthreads();
        #pragma unroll
        for (int u = 0; u < 4; ++u) {
            gld_lds16(sAp[u] + k0, (void*)(As + dst0 + u * 512));
            gld_lds16(sBp[u] + k0, (void*)(Bs + dst0 + u * 512));
        }
        asm volatile("s_waitcnt vmcnt(0)" ::: "memory");
        __syncthreads();

        #pragma unroll
        for (int kk = 0; kk < 2; ++kk) {
            bf16x8 af[4], bfr[4];
            #pragma unroll
            for (int i = 0; i < 4; ++i) af[i]  = *(const bf16x8*)&As[aoff[i][kk]];
            #pragma unroll
            for (int j = 0; j < 4; ++j) bfr[j] = *(const bf16x8*)&Bs[boff[j][kk]];
            #pragma unroll
            for (int i = 0; i < 4; ++i)
                #pragma unroll
                for (int j = 0; j < 4; ++j)
                    acc[i][j] = mfma16(af[i], bfr[j], acc[i][j]);
        }
    }

    const int rbase = m0 + 64 * wm + quad * 4;
    const int cbase = n0 + 64 * wn + l16;
    if (outF) {
        float bv[4];
        #pragma unroll
        for (int j = 0; j < 4; ++j) bv[j] = bias[cbase + 16 * j];
        #pragma unroll
        for (int i = 0; i < 4; ++i)
            #pragma unroll
            for (int r = 0; r < 4; ++r) {
                size_t ro = (size_t)(rbase + 16 * i + r) * N;
                #pragma unroll
                for (int j = 0; j < 4; ++j)
                    outF[ro + cbase + 16 * j] = acc[i][j][r] + bv[j];
            }
    } else {
        #pragma unroll
        for (int i = 0; i < 4; ++i)
            #pragma unroll
            for (int r = 0; r < 4; ++r) {
                size_t ro = (size_t)(rbase + 16 * i + r) * N;
                #pragma unroll
                for (int j = 0; j < 4; ++j)
                    outB[ro + cbase + 16 * j] = f2bf_hw(acc[i][j][r]);
            }
    }
}

// ---------------------------------------------------------------------------
// gemm1 with FUSED repack — BK=64 main loop, epilogue scatters into
// qb/kx/vx layouts directly (round-9 win).
// ---------------------------------------------------------------------------
__global__ __launch_bounds__(256, 3) void gemm_qkv_bt(
    const u16* __restrict__ A, const u16* __restrict__ Bt,
    u16* __restrict__ outQ, u16* __restrict__ kx, u16* __restrict__ vx)
{
    const int K = Cc;
    __shared__ u16 As[128 * 64];
    __shared__ u16 Bs[128 * 64];
    const int t = threadIdx.x;
    const int w = t >> 6, lane = t & 63;
    const int quad = lane >> 4, l16 = lane & 15;
    const int wm = w >> 1, wn = w & 1;
    const int m0 = blockIdx.y * 128, n0 = blockIdx.x * 128;

    const int l8r   = lane >> 3;
    const int g_log = (lane & 7) ^ l8r;
    const u16* sAp[4]; const u16* sBp[4];
    #pragma unroll
    for (int u = 0; u < 4; ++u) {
        const int gi = w * 4 + u;
        sAp[u] = A  + (size_t)(m0 + gi * 8 + l8r) * K + g_log * 8;
        sBp[u] = Bt + (size_t)(n0 + gi * 8 + l8r) * K + g_log * 8;
    }
    const int dst0 = w * 2048 + lane * 8;

    int aoff[4][2], boff[4][2];
    #pragma unroll
    for (int i = 0; i < 4; ++i) {
        const int rA = 64 * wm + 16 * i + l16;
        const int rB = 64 * wn + 16 * i + l16;
        #pragma unroll
        for (int kk = 0; kk < 2; ++kk) {
            aoff[i][kk] = rA * 64 + (((4 * kk + quad) ^ (rA & 7)) * 8);
            boff[i][kk] = rB * 64 + (((4 * kk + quad) ^ (rB & 7)) * 8);
        }
    }

    f32x4 acc[4][4] = {};

    for (int k0 = 0; k0 < K; k0 += 64) {
        __syncthreads();
        #pragma unroll
        for (int u = 0; u < 4; ++u) {
            gld_lds16(sAp[u] + k0, (void*)(As + dst0 + u * 512));
            gld_lds16(sBp[u] + k0, (void*)(Bs + dst0 + u * 512));
        }
        asm volatile("s_waitcnt vmcnt(0)" ::: "memory");
        __syncthreads();

        #pragma unroll
        for (int kk = 0; kk < 2; ++kk) {
            bf16x8 af[4], bfr[4];
            #pragma unroll
            for (int i = 0; i < 4; ++i) af[i]  = *(const bf16x8*)&As[aoff[i][kk]];
            #pragma unroll
            for (int j = 0; j < 4; ++j) bfr[j] = *(const bf16x8*)&Bs[boff[j][kk]];
            #pragma unroll
            for (int i = 0; i < 4; ++i)
                #pragma unroll
                for (int j = 0; j < 4; ++j)
                    acc[i][j] = mfma16(af[i], bfr[j], acc[i][j]);
        }
    }

    const int rbase = m0 + 64 * wm + quad * 4;      // + 16*i + r = global row
    const int cbase = n0 + 64 * wn + l16;           // + 16*j    = global col
    const int region = n0 >> 10;                    // 0=Q, 1=K, 2=V (uniform)

    if (region == 0) {
        #pragma unroll
        for (int i = 0; i < 4; ++i)
            #pragma unroll
            for (int r = 0; r < 4; ++r) {
                size_t ro = (size_t)(rbase + 16 * i + r) * Cc;
                #pragma unroll
                for (int j = 0; j < 4; ++j)
                    outQ[ro + cbase + 16 * j] = f2bf_hw(acc[i][j][r]);
            }
    } else if (region == 1) {
        int colK[4];
        #pragma unroll
        for (int j = 0; j < 4; ++j) {
            const int c = (cbase - 1024) + 16 * j;
            const int h = c >> 6, d = c & 63;
            colK[j] = h * 131072 + (d >> 5) * 512 + ((d >> 3) & 3) * 128 + (d & 7);
        }
        #pragma unroll
        for (int i = 0; i < 4; ++i)
            #pragma unroll
            for (int r = 0; r < 4; ++r) {
                const int row = rbase + 16 * i + r;
                const int b = row >> 11, key = row & 2047;
                const int ch = key >> 6, keyr = key & 63;
                const int rowK = b * 2097152 + ch * 4096 + (keyr >> 4) * 1024 + (keyr & 15) * 8;
                #pragma unroll
                for (int j = 0; j < 4; ++j)
                    kx[rowK + colK[j]] = f2bf_hw(acc[i][j][r]);
            }
    } else {
        int colV[4];
        #pragma unroll
        for (int j = 0; j < 4; ++j) {
            const int c = (cbase - 2048) + 16 * j;
            const int h = c >> 6, d = c & 63;
            colV[j] = h * 131072 + (d >> 4) * 1024 + (d & 15) * 8;
        }
        #pragma unroll
        for (int i = 0; i < 4; ++i)
            #pragma unroll
            for (int r = 0; r < 4; ++r) {
                const int row = rbase + 16 * i + r;
                const int b = row >> 11, key = row & 2047;
                const int ch = key >> 6, keyr = key & 63;
                const int rowV = b * 2097152 + ch * 4096 + (keyr >> 5) * 512
                               + ((keyr >> 3) & 3) * 128 + (keyr & 7);
                #pragma unroll
                for (int j = 0; j < 4; ++j)
                    vx[rowV + colV[j]] = f2bf_hw(acc[i][j][r]);
            }
    }
}

// ---------------------------------------------------------------------------
// Flash attention. Round-12 change: PHASE-SPLIT per chunk.
// Per-qq slabs (round 11, +3%) removed the WAR alias but the fine-grained
// 18-MFMA/30-VALU alternation still gives the CU scheduler only short
// windows to overlap the two blocks on a CU. This version clusters the
// chunk into three monolithic phases: all 32 S-MFMAs (st[4][4] carried in
// regs) -> all exp/pack/P-writes -> all 40 PV-MFMAs. The two independent
// blocks per CU drift anti-phase, so wave A's MFMA cluster can fill the
// matrix pipe while wave B runs its VALU cluster. Register growth (~+64
// VGPR) is FREE: launch_bounds(256,2) permits 256 VGPR at the grid-capped
// occupancy (2 blocks/CU, 2 waves/SIMD). Spill watchdog: WRITE_SIZE >>
// 16MB or VGPR=256 means spill -> revert.
// ---------------------------------------------------------------------------
__global__ __launch_bounds__(256, 2) void attn_mfma4(
    const u16* __restrict__ qb, const u16* __restrict__ kx, const u16* __restrict__ vx,
    const int* __restrict__ mask, u16* __restrict__ outO)
{
    __shared__ u16 KVs[8192];             // K:0..4095 | V:4096..8191  (16KB)
    __shared__ u16 Pss[4][4][16 * 68];    // per-wave PER-QQ P slabs   (34KB)

    const int t = threadIdx.x;
    const int w = t >> 6, lane = t & 63;
    const int quad = lane >> 4, l16 = lane & 15;
    const int bh = blockIdx.x, qblk = blockIdx.y, b = bh >> 4, h = bh & 15;

    // ---- valid length L from prefix mask ----
    int sum = 0;
    {
        const int4* mp = (const int4*)(mask + b * Tt) + lane * 8;
        #pragma unroll
        for (int i = 0; i < 8; ++i) { int4 m4 = mp[i]; sum += m4.x + m4.y + m4.z + m4.w; }
        #pragma unroll
        for (int off = 1; off < 64; off <<= 1) sum += __shfl_xor(sum, off);
    }
    const int L = sum;

    // ---- persistent Q fragments (pre-scaled at weight cast) ----
    const int q0 = qblk * 256 + w * 64;
    bf16x8 qf[4][2];
    #pragma unroll
    for (int qq = 0; qq < 4; ++qq) {
        const u16* qp = qb + (size_t)(b * Tt + q0 + 16 * qq + l16) * Cc + h * 64 + quad * 8;
        qf[qq][0] = *(const bf16x8*)(qp);
        qf[qq][1] = *(const bf16x8*)(qp + 32);
    }

    f32x4 oacc[4][4] = {};
    f32x4 lacc[4]    = {};
    const __bf16 onebf = (__bf16)1.0f;
    const bf16x8 ones  = {onebf, onebf, onebf, onebf, onebf, onebf, onebf, onebf};

    const int nfull = L >> 6;
    const int nch   = (L + 63) >> 6;
    const size_t cb0 = (size_t)bh * 32 * 4096;   // chunk stride 4096 u16

    // ---- prologue: chunk 0 -> regs -> LDS ----
    {
        uint4 k0a = *(const uint4*)&kx[cb0 + t * 8];
        uint4 k0b = *(const uint4*)&kx[cb0 + 2048 + t * 8];
        uint4 v0a = *(const uint4*)&vx[cb0 + t * 8];
        uint4 v0b = *(const uint4*)&vx[cb0 + 2048 + t * 8];
        *(uint4*)&KVs[t * 8]        = k0a;
        *(uint4*)&KVs[2048 + t * 8] = k0b;
        *(uint4*)&KVs[4096 + t * 8] = v0a;
        *(uint4*)&KVs[6144 + t * 8] = v0b;
    }
    __syncthreads();

    for (int ch = 0; ch < nch; ++ch) {
        // ---- T14: issue next-chunk loads now; first use is after barrier ----
        const int cc = (ch + 1 < nch) ? ch + 1 : ch;
        const size_t nb = cb0 + (size_t)cc * 4096;
        uint4 nk0 = *(const uint4*)&kx[nb + t * 8];
        uint4 nk1 = *(const uint4*)&kx[nb + 2048 + t * 8];
        uint4 nv0 = *(const uint4*)&vx[nb + t * 8];
        uint4 nv1 = *(const uint4*)&vx[nb + 2048 + t * 8];

        const u16* Kb = KVs;
        const u16* Vb = KVs + 4096;

        // ---- K fragments from LDS (linear, conflict-free) ----
        bf16x8 kf[4][2];
        #pragma unroll
        for (int jt = 0; jt < 4; ++jt)
            #pragma unroll
            for (int ks = 0; ks < 2; ++ks)
                kf[jt][ks] = *(const bf16x8*)&Kb[(jt * 2 + ks) * 512 + lane * 8];

        // ---- V fragments ----
        bf16x8 vf[4][2];
        #pragma unroll
        for (int dt = 0; dt < 4; ++dt)
            #pragma unroll
            for (int ks = 0; ks < 2; ++ks)
                vf[dt][ks] = *(const bf16x8*)&Vb[(dt * 2 + ks) * 512 + lane * 8];

        // ---- Phase A: ALL S-MFMAs (32), st carried in registers ----
        f32x4 st[4][4];
        __builtin_amdgcn_s_setprio(1);
        #pragma unroll
        for (int qq = 0; qq < 4; ++qq)
            #pragma unroll
            for (int jt = 0; jt < 4; ++jt) {
                f32x4 z = {0.f, 0.f, 0.f, 0.f};
                z = mfma16(kf[jt][0], qf[qq][0], z);
                st[qq][jt] = mfma16(kf[jt][1], qf[qq][1], z);
            }
        __builtin_amdgcn_s_setprio(0);

        // ---- Phase B: ALL exp/pack/P-writes ----
        if (ch < nfull) {
            #pragma unroll
            for (int qq = 0; qq < 4; ++qq)
                #pragma unroll
                for (int jt = 0; jt < 4; ++jt) {
                    uint2 pk;
                    pk.x = cvt_pk_bf16(fexp2(st[qq][jt][0]), fexp2(st[qq][jt][1]));
                    pk.y = cvt_pk_bf16(fexp2(st[qq][jt][2]), fexp2(st[qq][jt][3]));
                    *(uint2*)&Pss[w][qq][l16 * 68 + 16 * jt + quad * 4] = pk;
                }
        } else {
            const int kc = ch * 64;
            #pragma unroll
            for (int qq = 0; qq < 4; ++qq)
                #pragma unroll
                for (int jt = 0; jt < 4; ++jt) {
                    const int kb = kc + 16 * jt + quad * 4;
                    float e[4];
                    #pragma unroll
                    for (int r = 0; r < 4; ++r)
                        e[r] = (kb + r < L) ? fexp2(st[qq][jt][r]) : 0.f;
                    uint2 pk;
                    pk.x = cvt_pk_bf16(e[0], e[1]);
                    pk.y = cvt_pk_bf16(e[2], e[3]);
                    *(uint2*)&Pss[w][qq][l16 * 68 + 16 * jt + quad * 4] = pk;
                }
        }

        // ---- Phase C: ALL PV-MFMAs (40) ----
        __builtin_amdgcn_s_setprio(1);
        #pragma unroll
        for (int qq = 0; qq < 4; ++qq) {
            #pragma unroll
            for (int ks = 0; ks < 2; ++ks) {
                const u16* pr = &Pss[w][qq][l16 * 68 + 32 * ks + quad * 8];
                uint2 pa = *(const uint2*)pr;
                uint2 pb = *(const uint2*)(pr + 4);
                uint4 comb = {pa.x, pa.y, pb.x, pb.y};
                bf16x8 pf = *(const bf16x8*)&comb;
                #pragma unroll
                for (int dt = 0; dt < 4; ++dt)
                    oacc[qq][dt] = mfma16(pf, vf[dt][ks], oacc[qq][dt]);
                lacc[qq] = mfma16(pf, ones, lacc[qq]);
            }
        }
        __builtin_amdgcn_s_setprio(0);

        // ---- rotate buffer: all readers done -> write next chunk ----
        __syncthreads();
        *(uint4*)&KVs[t * 8]        = nk0;
        *(uint4*)&KVs[2048 + t * 8] = nk1;
        *(uint4*)&KVs[4096 + t * 8] = nv0;
        *(uint4*)&KVs[6144 + t * 8] = nv1;
        __syncthreads();
    }

    // ---- write O (bf16, [B*T, C]) ----
    #pragma unroll
    for (int qq = 0; qq < 4; ++qq)
        #pragma unroll
        for (int r = 0; r < 4; ++r) {
            const float inv = 1.f / lacc[qq][r];
            const size_t ro = (size_t)(b * Tt + q0 + 16 * qq + quad * 4 + r) * Cc + h * 64 + l16;
            #pragma unroll
            for (int dt = 0; dt < 4; ++dt)
                outO[ro + 16 * dt] = f2bf_hw(oacc[qq][dt][r] * inv);
        }
}

// ---------------------------------------------------------------------------
extern "C" void kernel_launch(void* const* d_in, const int* in_sizes, int n_in,
                              void* d_out, int out_size, void* d_ws, size_t ws_size,
                              hipStream_t stream) {
    const float* x     = (const float*)d_in[0];
    const int*   mask  = (const int*)  d_in[1];
    const float* w_qkv = (const float*)d_in[2];
    const float* w_out = (const float*)d_in[3];
    const float* b_out = (const float*)d_in[4];
    float*       outp  = (float*)d_out;

    const int M = Bb * Tt;                        // 8192
    char* ws = (char*)d_ws;
    u16* xb     = (u16*)(ws);                     // 16 MB  [M,C]  (dead after gemm1)
    u16* wqkvT  = (u16*)(ws + (16u << 20));       //  6 MB  [3C,C]
    u16* woutT  = (u16*)(ws + (22u << 20));       //  2 MB  [C,C]
    u16* qbuf   = (u16*)(ws + (24u << 20));       // 16 MB  compact Q [M,C]
    u16* kx     = (u16*)(ws + (40u << 20));       // 16 MB  frag-packed K
    u16* vx     = (u16*)(ws + (56u << 20));       // 16 MB  frag-packed V^T
    u16* attnO  = (u16*)(ws);                     // 16 MB  reuses xb region

    const float c2 = 0.18033688011112042f;        // 0.125 * log2(e), folded into Q weights

    // fused preprocessing: 1 launch (was 3)
    prep_cast<<<9216, 256, 0, stream>>>(x, xb, w_qkv, wqkvT, w_out, woutT, c2);

    // gemm1 with fused repack (BK=64): writes qbuf + kx + vx directly
    gemm_qkv_bt<<<dim3(3 * Cc / 128, M / 128), 256, 0, stream>>>(
        xb, wqkvT, qbuf, kx, vx);

    // attn: 4-wave blocks, QBLK=64/wave, per-qq P slabs, phase-split
    attn_mfma4<<<dim3(Bb * Hh, Tt / 256), 256, 0, stream>>>(qbuf, kx, vx, mask, attnO);

    gemm_bt_bf16<<<dim3(Cc / 128, M / 128), 256, 0, stream>>>(
        attnO, woutT, b_out, nullptr, outp, M, Cc, Cc);
}

// Round 13
// 239.478 us; speedup vs baseline: 1.2318x; 1.2318x over previous
//
#include <hip/hip_runtime.h>
#include <hip/hip_bf16.h>

// (B,T,C,H) = (4,2048,1024,16), D=64
#define Bb 4
#define Tt 2048
#define Cc 1024
#define Hh 16

typedef unsigned short u16;
typedef __attribute__((ext_vector_type(8))) __bf16 bf16x8;
typedef __attribute__((ext_vector_type(4))) float  f32x4;

__device__ __forceinline__ u16 f2bf_hw(float f) {         // native cvt on gfx950
    __bf16 h = (__bf16)f;
    return *(u16*)&h;
}

// v_cvt_pk_bf16_f32: low16 = bf16(a), high16 = bf16(b)
__device__ __forceinline__ unsigned cvt_pk_bf16(float a, float b) {
    unsigned r;
    asm("v_cvt_pk_bf16_f32 %0, %1, %2" : "=v"(r) : "v"(a), "v"(b));
    return r;
}

__device__ __forceinline__ float fexp2(float x) {
#if __has_builtin(__builtin_amdgcn_exp2f)
    return __builtin_amdgcn_exp2f(x);
#else
    return __expf(x * 0.6931471805599453f);
#endif
}

__device__ __forceinline__ void gld_lds16(const void* g, void* l) {
    __builtin_amdgcn_global_load_lds(
        (__attribute__((address_space(1))) void*)(g),
        (__attribute__((address_space(3))) void*)(l),
        16, 0, 0);
}

__device__ __forceinline__ f32x4 mfma16(bf16x8 a, bf16x8 b, f32x4 c) {
    return __builtin_amdgcn_mfma_f32_16x16x32_bf16(a, b, c, 0, 0, 0);
}

// ---------------------------------------------------------------------------
// Fused preprocessing: one launch replaces the x-cast + 2 weight castT's.
// Region decode on 1D grid: [0,8192) cast-x; [8192,8960) castT w_qkv;
// [8960,9216) castT w_out.
// ---------------------------------------------------------------------------
__device__ void castT_body(const float* __restrict__ in, u16* __restrict__ out,
                           int K, int N, int scaleN, float sv,
                           int bx, int by, float Ls[64][65]) {
    const int n0 = bx * 64, k0 = by * 64;
    const int t = threadIdx.x;
    #pragma unroll
    for (int s = 0; s < 4; ++s) {
        int idx = t + 256 * s;
        int r   = idx >> 4;
        int c4  = (idx & 15) * 4;
        float4 v = *(const float4*)&in[(size_t)(k0 + r) * N + n0 + c4];
        Ls[r][c4 + 0] = v.x; Ls[r][c4 + 1] = v.y;
        Ls[r][c4 + 2] = v.z; Ls[r][c4 + 3] = v.w;
    }
    __syncthreads();
    #pragma unroll
    for (int s = 0; s < 2; ++s) {
        int idx = t + 256 * s;
        int n   = idx >> 3;
        int kc  = (idx & 7) * 8;
        const float sc = (n0 + n < scaleN) ? sv : 1.0f;
        alignas(16) u16 tmp[8];
        #pragma unroll
        for (int i = 0; i < 8; ++i) tmp[i] = f2bf_hw(Ls[kc + i][n] * sc);
        *(uint4*)&out[(size_t)(n0 + n) * K + k0 + kc] = *(const uint4*)tmp;
    }
}

__global__ void prep_cast(const float* __restrict__ x, u16* __restrict__ xb,
                          const float* __restrict__ w_qkv, u16* __restrict__ wqkvT,
                          const float* __restrict__ w_out, u16* __restrict__ woutT,
                          float c2) {
    __shared__ float Ls[64][65];
    const int id = blockIdx.x;
    if (id < 8192) {
        // cast x [M,C] f32 -> bf16, 4 f32/thread; 8192*256*4 = exactly M*C
        const int i = id * 256 + threadIdx.x;
        float4 v = ((const float4*)x)[i];
        uint2 o;
        o.x = cvt_pk_bf16(v.x, v.y);
        o.y = cvt_pk_bf16(v.z, v.w);
        ((uint2*)xb)[i] = o;
    } else if (id < 8192 + 768) {
        const int r = id - 8192;                 // 48 x 16
        castT_body(w_qkv, wqkvT, Cc, 3 * Cc, Cc, c2, r % 48, r / 48, Ls);
    } else {
        const int r = id - 8960;                 // 16 x 16
        castT_body(w_out, woutT, Cc, Cc, 0, 1.0f, r % 16, r / 16, Ls);
    }
}

// ---------------------------------------------------------------------------
// bf16 GEMM, B^T input — BK=64 m97 structure (round-10 win: 32->16 drain
// points, 128^2 tile, 3 blocks/CU). gemm2 only.
// ---------------------------------------------------------------------------
__global__ __launch_bounds__(256, 3) void gemm_bt_bf16(
    const u16* __restrict__ A, const u16* __restrict__ Bt,
    const float* __restrict__ bias,
    u16* __restrict__ outB, float* __restrict__ outF,
    int M, int N, int K)
{
    __shared__ u16 As[128 * 64];
    __shared__ u16 Bs[128 * 64];
    const int t = threadIdx.x;
    const int w = t >> 6, lane = t & 63;
    const int quad = lane >> 4, l16 = lane & 15;
    const int wm = w >> 1, wn = w & 1;
    const int m0 = blockIdx.y * 128, n0 = blockIdx.x * 128;

    const int l8r   = lane >> 3;
    const int g_log = (lane & 7) ^ l8r;
    const u16* sAp[4]; const u16* sBp[4];
    #pragma unroll
    for (int u = 0; u < 4; ++u) {
        const int gi = w * 4 + u;                     // [0,16)
        sAp[u] = A  + (size_t)(m0 + gi * 8 + l8r) * K + g_log * 8;
        sBp[u] = Bt + (size_t)(n0 + gi * 8 + l8r) * K + g_log * 8;
    }
    const int dst0 = w * 2048 + lane * 8;             // u16 units

    int aoff[4][2], boff[4][2];
    #pragma unroll
    for (int i = 0; i < 4; ++i) {
        const int rA = 64 * wm + 16 * i + l16;
        const int rB = 64 * wn + 16 * i + l16;
        #pragma unroll
        for (int kk = 0; kk < 2; ++kk) {
            aoff[i][kk] = rA * 64 + (((4 * kk + quad) ^ (rA & 7)) * 8);
            boff[i][kk] = rB * 64 + (((4 * kk + quad) ^ (rB & 7)) * 8);
        }
    }

    f32x4 acc[4][4] = {};

    for (int k0 = 0; k0 < K; k0 += 64) {
        __syncthreads();
        #pragma unroll
        for (int u = 0; u < 4; ++u) {
            gld_lds16(sAp[u] + k0, (void*)(As + dst0 + u * 512));
            gld_lds16(sBp[u] + k0, (void*)(Bs + dst0 + u * 512));
        }
        asm volatile("s_waitcnt vmcnt(0)" ::: "memory");
        __syncthreads();

        #pragma unroll
        for (int kk = 0; kk < 2; ++kk) {
            bf16x8 af[4], bfr[4];
            #pragma unroll
            for (int i = 0; i < 4; ++i) af[i]  = *(const bf16x8*)&As[aoff[i][kk]];
            #pragma unroll
            for (int j = 0; j < 4; ++j) bfr[j] = *(const bf16x8*)&Bs[boff[j][kk]];
            #pragma unroll
            for (int i = 0; i < 4; ++i)
                #pragma unroll
                for (int j = 0; j < 4; ++j)
                    acc[i][j] = mfma16(af[i], bfr[j], acc[i][j]);
        }
    }

    const int rbase = m0 + 64 * wm + quad * 4;
    const int cbase = n0 + 64 * wn + l16;
    if (outF) {
        float bv[4];
        #pragma unroll
        for (int j = 0; j < 4; ++j) bv[j] = bias[cbase + 16 * j];
        #pragma unroll
        for (int i = 0; i < 4; ++i)
            #pragma unroll
            for (int r = 0; r < 4; ++r) {
                size_t ro = (size_t)(rbase + 16 * i + r) * N;
                #pragma unroll
                for (int j = 0; j < 4; ++j)
                    outF[ro + cbase + 16 * j] = acc[i][j][r] + bv[j];
            }
    } else {
        #pragma unroll
        for (int i = 0; i < 4; ++i)
            #pragma unroll
            for (int r = 0; r < 4; ++r) {
                size_t ro = (size_t)(rbase + 16 * i + r) * N;
                #pragma unroll
                for (int j = 0; j < 4; ++j)
                    outB[ro + cbase + 16 * j] = f2bf_hw(acc[i][j][r]);
            }
    }
}

// ---------------------------------------------------------------------------
// gemm1 with FUSED repack — BK=64 main loop, epilogue scatters into
// qb/kx/vx layouts directly (round-9 win).
// ---------------------------------------------------------------------------
__global__ __launch_bounds__(256, 3) void gemm_qkv_bt(
    const u16* __restrict__ A, const u16* __restrict__ Bt,
    u16* __restrict__ outQ, u16* __restrict__ kx, u16* __restrict__ vx)
{
    const int K = Cc;
    __shared__ u16 As[128 * 64];
    __shared__ u16 Bs[128 * 64];
    const int t = threadIdx.x;
    const int w = t >> 6, lane = t & 63;
    const int quad = lane >> 4, l16 = lane & 15;
    const int wm = w >> 1, wn = w & 1;
    const int m0 = blockIdx.y * 128, n0 = blockIdx.x * 128;

    const int l8r   = lane >> 3;
    const int g_log = (lane & 7) ^ l8r;
    const u16* sAp[4]; const u16* sBp[4];
    #pragma unroll
    for (int u = 0; u < 4; ++u) {
        const int gi = w * 4 + u;
        sAp[u] = A  + (size_t)(m0 + gi * 8 + l8r) * K + g_log * 8;
        sBp[u] = Bt + (size_t)(n0 + gi * 8 + l8r) * K + g_log * 8;
    }
    const int dst0 = w * 2048 + lane * 8;

    int aoff[4][2], boff[4][2];
    #pragma unroll
    for (int i = 0; i < 4; ++i) {
        const int rA = 64 * wm + 16 * i + l16;
        const int rB = 64 * wn + 16 * i + l16;
        #pragma unroll
        for (int kk = 0; kk < 2; ++kk) {
            aoff[i][kk] = rA * 64 + (((4 * kk + quad) ^ (rA & 7)) * 8);
            boff[i][kk] = rB * 64 + (((4 * kk + quad) ^ (rB & 7)) * 8);
        }
    }

    f32x4 acc[4][4] = {};

    for (int k0 = 0; k0 < K; k0 += 64) {
        __syncthreads();
        #pragma unroll
        for (int u = 0; u < 4; ++u) {
            gld_lds16(sAp[u] + k0, (void*)(As + dst0 + u * 512));
            gld_lds16(sBp[u] + k0, (void*)(Bs + dst0 + u * 512));
        }
        asm volatile("s_waitcnt vmcnt(0)" ::: "memory");
        __syncthreads();

        #pragma unroll
        for (int kk = 0; kk < 2; ++kk) {
            bf16x8 af[4], bfr[4];
            #pragma unroll
            for (int i = 0; i < 4; ++i) af[i]  = *(const bf16x8*)&As[aoff[i][kk]];
            #pragma unroll
            for (int j = 0; j < 4; ++j) bfr[j] = *(const bf16x8*)&Bs[boff[j][kk]];
            #pragma unroll
            for (int i = 0; i < 4; ++i)
                #pragma unroll
                for (int j = 0; j < 4; ++j)
                    acc[i][j] = mfma16(af[i], bfr[j], acc[i][j]);
        }
    }

    const int rbase = m0 + 64 * wm + quad * 4;      // + 16*i + r = global row
    const int cbase = n0 + 64 * wn + l16;           // + 16*j    = global col
    const int region = n0 >> 10;                    // 0=Q, 1=K, 2=V (uniform)

    if (region == 0) {
        #pragma unroll
        for (int i = 0; i < 4; ++i)
            #pragma unroll
            for (int r = 0; r < 4; ++r) {
                size_t ro = (size_t)(rbase + 16 * i + r) * Cc;
                #pragma unroll
                for (int j = 0; j < 4; ++j)
                    outQ[ro + cbase + 16 * j] = f2bf_hw(acc[i][j][r]);
            }
    } else if (region == 1) {
        int colK[4];
        #pragma unroll
        for (int j = 0; j < 4; ++j) {
            const int c = (cbase - 1024) + 16 * j;
            const int h = c >> 6, d = c & 63;
            colK[j] = h * 131072 + (d >> 5) * 512 + ((d >> 3) & 3) * 128 + (d & 7);
        }
        #pragma unroll
        for (int i = 0; i < 4; ++i)
            #pragma unroll
            for (int r = 0; r < 4; ++r) {
                const int row = rbase + 16 * i + r;
                const int b = row >> 11, key = row & 2047;
                const int ch = key >> 6, keyr = key & 63;
                const int rowK = b * 2097152 + ch * 4096 + (keyr >> 4) * 1024 + (keyr & 15) * 8;
                #pragma unroll
                for (int j = 0; j < 4; ++j)
                    kx[rowK + colK[j]] = f2bf_hw(acc[i][j][r]);
            }
    } else {
        int colV[4];
        #pragma unroll
        for (int j = 0; j < 4; ++j) {
            const int c = (cbase - 2048) + 16 * j;
            const int h = c >> 6, d = c & 63;
            colV[j] = h * 131072 + (d >> 4) * 1024 + (d & 15) * 8;
        }
        #pragma unroll
        for (int i = 0; i < 4; ++i)
            #pragma unroll
            for (int r = 0; r < 4; ++r) {
                const int row = rbase + 16 * i + r;
                const int b = row >> 11, key = row & 2047;
                const int ch = key >> 6, keyr = key & 63;
                const int rowV = b * 2097152 + ch * 4096 + (keyr >> 5) * 512
                               + ((keyr >> 3) & 3) * 128 + (keyr & 7);
                #pragma unroll
                for (int j = 0; j < 4; ++j)
                    vx[rowV + colV[j]] = f2bf_hw(acc[i][j][r]);
            }
    }
}

// ---------------------------------------------------------------------------
// Flash attention — ROUND-11 VERSION RESTORED (73.1us, VGPR 128, no spill).
// Round-12 phase-split spilled: the allocator would not cross the 128-VGPR
// occupancy step despite launch_bounds(256,2) permitting 256, and spilled
// the st[4][4] carry to scratch (WRITE_SIZE 16->35MB, attn 73->119us).
// Lesson: launch_bounds headroom is not allocator headroom; live sets must
// fit the current VGPR step. Per-qq P slabs (round-11 +3%) retained:
// removes the WAR alias between qq iterations so S(qq+1) can overlap
// exp/pack(qq). 4 waves/block, QBLK=64/wave, single-buffer KV + T14 reg
// prefetch.
// ---------------------------------------------------------------------------
__global__ __launch_bounds__(256, 2) void attn_mfma4(
    const u16* __restrict__ qb, const u16* __restrict__ kx, const u16* __restrict__ vx,
    const int* __restrict__ mask, u16* __restrict__ outO)
{
    __shared__ u16 KVs[8192];             // K:0..4095 | V:4096..8191  (16KB)
    __shared__ u16 Pss[4][4][16 * 68];    // per-wave PER-QQ P slabs   (34KB)

    const int t = threadIdx.x;
    const int w = t >> 6, lane = t & 63;
    const int quad = lane >> 4, l16 = lane & 15;
    const int bh = blockIdx.x, qblk = blockIdx.y, b = bh >> 4, h = bh & 15;

    // ---- valid length L from prefix mask ----
    int sum = 0;
    {
        const int4* mp = (const int4*)(mask + b * Tt) + lane * 8;
        #pragma unroll
        for (int i = 0; i < 8; ++i) { int4 m4 = mp[i]; sum += m4.x + m4.y + m4.z + m4.w; }
        #pragma unroll
        for (int off = 1; off < 64; off <<= 1) sum += __shfl_xor(sum, off);
    }
    const int L = sum;

    // ---- persistent Q fragments (pre-scaled at weight cast) ----
    const int q0 = qblk * 256 + w * 64;
    bf16x8 qf[4][2];
    #pragma unroll
    for (int qq = 0; qq < 4; ++qq) {
        const u16* qp = qb + (size_t)(b * Tt + q0 + 16 * qq + l16) * Cc + h * 64 + quad * 8;
        qf[qq][0] = *(const bf16x8*)(qp);
        qf[qq][1] = *(const bf16x8*)(qp + 32);
    }

    f32x4 oacc[4][4] = {};
    f32x4 lacc[4]    = {};
    const __bf16 onebf = (__bf16)1.0f;
    const bf16x8 ones  = {onebf, onebf, onebf, onebf, onebf, onebf, onebf, onebf};

    const int nfull = L >> 6;
    const int nch   = (L + 63) >> 6;
    const size_t cb0 = (size_t)bh * 32 * 4096;   // chunk stride 4096 u16

    // ---- prologue: chunk 0 -> regs -> LDS ----
    {
        uint4 k0a = *(const uint4*)&kx[cb0 + t * 8];
        uint4 k0b = *(const uint4*)&kx[cb0 + 2048 + t * 8];
        uint4 v0a = *(const uint4*)&vx[cb0 + t * 8];
        uint4 v0b = *(const uint4*)&vx[cb0 + 2048 + t * 8];
        *(uint4*)&KVs[t * 8]        = k0a;
        *(uint4*)&KVs[2048 + t * 8] = k0b;
        *(uint4*)&KVs[4096 + t * 8] = v0a;
        *(uint4*)&KVs[6144 + t * 8] = v0b;
    }
    __syncthreads();

    for (int ch = 0; ch < nch; ++ch) {
        // ---- T14: issue next-chunk loads now; first use is after barrier ----
        const int cc = (ch + 1 < nch) ? ch + 1 : ch;
        const size_t nb = cb0 + (size_t)cc * 4096;
        uint4 nk0 = *(const uint4*)&kx[nb + t * 8];
        uint4 nk1 = *(const uint4*)&kx[nb + 2048 + t * 8];
        uint4 nv0 = *(const uint4*)&vx[nb + t * 8];
        uint4 nv1 = *(const uint4*)&vx[nb + 2048 + t * 8];

        const u16* Kb = KVs;
        const u16* Vb = KVs + 4096;

        // ---- K fragments from LDS (linear, conflict-free) ----
        bf16x8 kf[4][2];
        #pragma unroll
        for (int jt = 0; jt < 4; ++jt)
            #pragma unroll
            for (int ks = 0; ks < 2; ++ks)
                kf[jt][ks] = *(const bf16x8*)&Kb[(jt * 2 + ks) * 512 + lane * 8];

        // ---- V fragments ----
        bf16x8 vf[4][2];
        #pragma unroll
        for (int dt = 0; dt < 4; ++dt)
            #pragma unroll
            for (int ks = 0; ks < 2; ++ks)
                vf[dt][ks] = *(const bf16x8*)&Vb[(dt * 2 + ks) * 512 + lane * 8];

        // ---- per q-tile: S, exp, per-qq P slab, PV ----
        #pragma unroll
        for (int qq = 0; qq < 4; ++qq) {
            u16* Pw = Pss[w][qq];
            f32x4 st[4];
            __builtin_amdgcn_s_setprio(1);
            #pragma unroll
            for (int jt = 0; jt < 4; ++jt) {
                f32x4 z = {0.f, 0.f, 0.f, 0.f};
                z = mfma16(kf[jt][0], qf[qq][0], z);
                st[jt] = mfma16(kf[jt][1], qf[qq][1], z);
            }
            __builtin_amdgcn_s_setprio(0);
            uint2 pk[4];
            if (ch < nfull) {
                #pragma unroll
                for (int jt = 0; jt < 4; ++jt) {
                    pk[jt].x = cvt_pk_bf16(fexp2(st[jt][0]), fexp2(st[jt][1]));
                    pk[jt].y = cvt_pk_bf16(fexp2(st[jt][2]), fexp2(st[jt][3]));
                }
            } else {
                const int kc = ch * 64;
                #pragma unroll
                for (int jt = 0; jt < 4; ++jt) {
                    const int kb = kc + 16 * jt + quad * 4;
                    float e[4];
                    #pragma unroll
                    for (int r = 0; r < 4; ++r)
                        e[r] = (kb + r < L) ? fexp2(st[jt][r]) : 0.f;
                    pk[jt].x = cvt_pk_bf16(e[0], e[1]);
                    pk[jt].y = cvt_pk_bf16(e[2], e[3]);
                }
            }
            #pragma unroll
            for (int jt = 0; jt < 4; ++jt)
                *(uint2*)&Pw[l16 * 68 + 16 * jt + quad * 4] = pk[jt];

            __builtin_amdgcn_s_setprio(1);
            #pragma unroll
            for (int ks = 0; ks < 2; ++ks) {
                const u16* pr = &Pw[l16 * 68 + 32 * ks + quad * 8];
                uint2 pa = *(const uint2*)pr;
                uint2 pb = *(const uint2*)(pr + 4);
                uint4 comb = {pa.x, pa.y, pb.x, pb.y};
                bf16x8 pf = *(const bf16x8*)&comb;
                #pragma unroll
                for (int dt = 0; dt < 4; ++dt)
                    oacc[qq][dt] = mfma16(pf, vf[dt][ks], oacc[qq][dt]);
                lacc[qq] = mfma16(pf, ones, lacc[qq]);
            }
            __builtin_amdgcn_s_setprio(0);
        }

        // ---- rotate buffer: all readers done -> write next chunk ----
        __syncthreads();
        *(uint4*)&KVs[t * 8]        = nk0;
        *(uint4*)&KVs[2048 + t * 8] = nk1;
        *(uint4*)&KVs[4096 + t * 8] = nv0;
        *(uint4*)&KVs[6144 + t * 8] = nv1;
        __syncthreads();
    }

    // ---- write O (bf16, [B*T, C]) ----
    #pragma unroll
    for (int qq = 0; qq < 4; ++qq)
        #pragma unroll
        for (int r = 0; r < 4; ++r) {
            const float inv = 1.f / lacc[qq][r];
            const size_t ro = (size_t)(b * Tt + q0 + 16 * qq + quad * 4 + r) * Cc + h * 64 + l16;
            #pragma unroll
            for (int dt = 0; dt < 4; ++dt)
                outO[ro + 16 * dt] = f2bf_hw(oacc[qq][dt][r] * inv);
        }
}

// ---------------------------------------------------------------------------
extern "C" void kernel_launch(void* const* d_in, const int* in_sizes, int n_in,
                              void* d_out, int out_size, void* d_ws, size_t ws_size,
                              hipStream_t stream) {
    const float* x     = (const float*)d_in[0];
    const int*   mask  = (const int*)  d_in[1];
    const float* w_qkv = (const float*)d_in[2];
    const float* w_out = (const float*)d_in[3];
    const float* b_out = (const float*)d_in[4];
    float*       outp  = (float*)d_out;

    const int M = Bb * Tt;                        // 8192
    char* ws = (char*)d_ws;
    u16* xb     = (u16*)(ws);                     // 16 MB  [M,C]  (dead after gemm1)
    u16* wqkvT  = (u16*)(ws + (16u << 20));       //  6 MB  [3C,C]
    u16* woutT  = (u16*)(ws + (22u << 20));       //  2 MB  [C,C]
    u16* qbuf   = (u16*)(ws + (24u << 20));       // 16 MB  compact Q [M,C]
    u16* kx     = (u16*)(ws + (40u << 20));       // 16 MB  frag-packed K
    u16* vx     = (u16*)(ws + (56u << 20));       // 16 MB  frag-packed V^T
    u16* attnO  = (u16*)(ws);                     // 16 MB  reuses xb region

    const float c2 = 0.18033688011112042f;        // 0.125 * log2(e), folded into Q weights

    // fused preprocessing: 1 launch (was 3)
    prep_cast<<<9216, 256, 0, stream>>>(x, xb, w_qkv, wqkvT, w_out, woutT, c2);

    // gemm1 with fused repack (BK=64): writes qbuf + kx + vx directly
    gemm_qkv_bt<<<dim3(3 * Cc / 128, M / 128), 256, 0, stream>>>(
        xb, wqkvT, qbuf, kx, vx);

    // attn: 4-wave blocks, QBLK=64/wave, per-qq P slabs (round-11 version)
    attn_mfma4<<<dim3(Bb * Hh, Tt / 256), 256, 0, stream>>>(qbuf, kx, vx, mask, attnO);

    gemm_bt_bf16<<<dim3(Cc / 128, M / 128), 256, 0, stream>>>(
        attnO, woutT, b_out, nullptr, outp, M, Cc, Cc);
}